// Round 2
// baseline (120.804 us; speedup 1.0000x reference)
//
#include <hip/hip_runtime.h>
#include <hip/hip_bf16.h>

#define BB    262144
#define INF   256
#define HIDF  128
#define OUTF  15
#define NCAM  15
#define TM    128
#define MAXTILES (BB/TM + NCAM)   // 2063

typedef __attribute__((ext_vector_type(8))) short          bf16x8;
typedef __attribute__((ext_vector_type(4))) float          floatx4;
typedef __attribute__((ext_vector_type(4))) unsigned int   uintx4;
typedef __attribute__((ext_vector_type(8))) unsigned short ushortx8;

__device__ __forceinline__ unsigned short f2bf1(float a){
  unsigned int u = __builtin_bit_cast(unsigned int, a);
  u += 0x7fffu + ((u >> 16) & 1u);          // round-to-nearest-even
  return (unsigned short)(u >> 16);
}
__device__ __forceinline__ unsigned int f2bf2(float a, float b){
  return (unsigned int)f2bf1(a) | ((unsigned int)f2bf1(b) << 16);
}

// ---------- counting sort by camera ----------
__global__ void k_hist(const int* __restrict__ cam, int* __restrict__ counts, int n){
  __shared__ int lc[NCAM];
  int t = threadIdx.x;
  if (t < NCAM) lc[t] = 0;
  __syncthreads();
  for (int i = blockIdx.x*blockDim.x + t; i < n; i += gridDim.x*blockDim.x)
    atomicAdd(&lc[cam[i]], 1);
  __syncthreads();
  if (t < NCAM && lc[t]) atomicAdd(&counts[t], lc[t]);
}

__global__ void k_scan(const int* __restrict__ counts, int* __restrict__ offsets,
                       int* __restrict__ scatterOfs){
  if (threadIdx.x == 0){
    int s = 0;
    for (int c = 0; c < NCAM; ++c){ offsets[c] = s; scatterOfs[c] = s; s += counts[c]; }
    offsets[NCAM] = s;
  }
}

__global__ void k_scatter(const int* __restrict__ cam, int* __restrict__ scatterOfs,
                          int* __restrict__ idx, int n){
  __shared__ int lc[NCAM];
  __shared__ int base[NCAM];
  int t = threadIdx.x;
  if (t < NCAM) lc[t] = 0;
  __syncthreads();
  int start = blockIdx.x * 4096;
  int camr[16], lpos[16];
  #pragma unroll
  for (int j = 0; j < 16; ++j){
    int i = start + j*256 + t;
    if (i < n){ camr[j] = cam[i]; lpos[j] = atomicAdd(&lc[camr[j]], 1); }
    else camr[j] = -1;
  }
  __syncthreads();
  if (t < NCAM) base[t] = atomicAdd(&scatterOfs[t], lc[t]);
  __syncthreads();
  #pragma unroll
  for (int j = 0; j < 16; ++j){
    if (camr[j] >= 0){
      int i = start + j*256 + t;
      idx[base[camr[j]] + lpos[j]] = i;
    }
  }
}

// ---------- weight prepack to bf16 MFMA B-fragment layout ----------
// W1p elem offset = ((c*8 + nf)*8 + kf)*512 + lane*8 + j
//   holds W1[c][kf*32 + (lane>>4)*8 + j][nf*16 + (lane&15)]
__global__ void k_prepW1(const float* __restrict__ W1, unsigned short* __restrict__ W1p){
  int t = blockIdx.x * blockDim.x + threadIdx.x;
  int l  = t & 63;
  int kf = (t >> 6) & 7;
  int nf = (t >> 9) & 7;
  int c  = t >> 12;
  if (c >= NCAM) return;
  int col = nf*16 + (l & 15);
  int k0  = kf*32 + (l >> 4)*8;
  ushortx8 v;
  #pragma unroll
  for (int j = 0; j < 8; ++j)
    v[j] = f2bf1(W1[((size_t)c*INF + k0 + j)*HIDF + col]);
  *reinterpret_cast<ushortx8*>(W1p + (size_t)t*8) = v;
}

// W2p elem offset = (c*4 + kf)*512 + lane*8 + j ; N padded 15->16 with zeros
__global__ void k_prepW2(const float* __restrict__ W2, unsigned short* __restrict__ W2p){
  int t = blockIdx.x * blockDim.x + threadIdx.x;
  int l  = t & 63;
  int kf = (t >> 6) & 3;
  int c  = t >> 8;
  if (c >= NCAM) return;
  int col = l & 15;
  int k0  = kf*32 + (l >> 4)*8;
  ushortx8 v;
  #pragma unroll
  for (int j = 0; j < 8; ++j){
    float f = (col < OUTF) ? W2[((size_t)c*HIDF + k0 + j)*OUTF + col] : 0.0f;
    v[j] = f2bf1(f);
  }
  *reinterpret_cast<ushortx8*>(W2p + (size_t)t*8) = v;
}

// ---------- main fused MLP ----------
__global__ __launch_bounds__(256) void k_mlp(
    const float* __restrict__ x, const int* __restrict__ idx,
    const int* __restrict__ counts, const int* __restrict__ offsets,
    const unsigned short* __restrict__ W1p, const unsigned short* __restrict__ W2p,
    const float* __restrict__ b1, const float* __restrict__ b2,
    float* __restrict__ out)
{
  __shared__ int sidx[TM];
  __shared__ unsigned short hbuf[TM][HIDF];   // 32 KB, XOR-swizzled columns

  // map blockIdx -> (camera, tile)
  int bid = blockIdx.x;
  int c = -1, segStart = 0, rowStart = 0, rows = 0;
  {
    int cum = 0;
    #pragma unroll 1
    for (int cc = 0; cc < NCAM; ++cc){
      int n  = counts[cc];
      int nt = (n + TM - 1) / TM;
      if (c < 0 && bid < cum + nt){
        c = cc;
        int ti = bid - cum;
        rowStart = ti * TM;
        segStart = offsets[cc];
        rows = n - rowStart; if (rows > TM) rows = TM;
      }
      cum += nt;
    }
  }
  if (c < 0) return;

  int t = threadIdx.x;
  if (t < TM){
    int r = (t < rows) ? t : (rows - 1);
    sidx[t] = idx[segStart + rowStart + r];
  }
  __syncthreads();

  int wave = t >> 6, lane = t & 63;
  int wr  = wave * 32;                 // 4x1 wave grid: each wave owns 32 rows, all 128 cols
  int l15 = lane & 15, lk8 = (lane >> 4) * 8, lk4 = (lane >> 4) * 4;

  const float* aptr[2];
  #pragma unroll
  for (int mf = 0; mf < 2; ++mf)
    aptr[mf] = x + (size_t)sidx[wr + mf*16 + l15] * INF + lk8;

  const unsigned short* bbase = W1p + (size_t)c*32768 + lane*8;

  floatx4 acc[2][8];
  #pragma unroll
  for (int i = 0; i < 2; ++i)
    #pragma unroll
    for (int j = 0; j < 8; ++j) acc[i][j] = (floatx4)0.0f;

  for (int kf = 0; kf < 8; ++kf){
    bf16x8 bf[8];
    #pragma unroll
    for (int nf = 0; nf < 8; ++nf)
      bf[nf] = *reinterpret_cast<const bf16x8*>(bbase + nf*4096 + kf*512);
    bf16x8 af[2];
    #pragma unroll
    for (int mf = 0; mf < 2; ++mf){
      const float* p = aptr[mf] + kf*32;
      floatx4 f0 = *reinterpret_cast<const floatx4*>(p);
      floatx4 f1 = *reinterpret_cast<const floatx4*>(p + 4);
      uintx4 u;
      u[0] = f2bf2(f0[0], f0[1]); u[1] = f2bf2(f0[2], f0[3]);
      u[2] = f2bf2(f1[0], f1[1]); u[3] = f2bf2(f1[2], f1[3]);
      af[mf] = __builtin_bit_cast(bf16x8, u);
    }
    #pragma unroll
    for (int mf = 0; mf < 2; ++mf)
      #pragma unroll
      for (int nf = 0; nf < 8; ++nf)
        acc[mf][nf] = __builtin_amdgcn_mfma_f32_16x16x32_bf16(af[mf], bf[nf], acc[mf][nf], 0, 0, 0);
  }

  // layer-1 epilogue: bias + relu -> swizzled LDS (bf16)
  #pragma unroll
  for (int nf = 0; nf < 8; ++nf){
    int col = nf*16 + l15;
    float bias = b1[c*HIDF + col];
    #pragma unroll
    for (int mf = 0; mf < 2; ++mf){
      #pragma unroll
      for (int j = 0; j < 4; ++j){
        int row = wr + mf*16 + lk4 + j;
        float h = fmaxf(acc[mf][nf][j] + bias, 0.0f);
        int cb = (col*2) ^ ((row & 7) << 4);
        *reinterpret_cast<unsigned short*>(
            reinterpret_cast<char*>(&hbuf[row][0]) + cb) = f2bf1(h);
      }
    }
  }
  __syncthreads();

  // layer 2: [32 rows x 128] x [128 x 16(pad)]
  floatx4 acc2[2];
  acc2[0] = (floatx4)0.0f; acc2[1] = (floatx4)0.0f;
  const unsigned short* wb = W2p + (size_t)c*2048 + lane*8;
  #pragma unroll
  for (int kf = 0; kf < 4; ++kf){
    bf16x8 wv = *reinterpret_cast<const bf16x8*>(wb + kf*512);
    #pragma unroll
    for (int mf = 0; mf < 2; ++mf){
      int row = wr + mf*16 + l15;
      int cb = ((kf*32 + lk8)*2) ^ ((row & 7) << 4);
      bf16x8 av = *reinterpret_cast<const bf16x8*>(
          reinterpret_cast<char*>(&hbuf[row][0]) + cb);
      acc2[mf] = __builtin_amdgcn_mfma_f32_16x16x32_bf16(av, wv, acc2[mf], 0, 0, 0);
    }
  }

  int col = l15;
  if (col < OUTF){
    float bias2 = b2[c*OUTF + col];
    #pragma unroll
    for (int mf = 0; mf < 2; ++mf){
      #pragma unroll
      for (int j = 0; j < 4; ++j){
        int r = wr + mf*16 + lk4 + j;
        if (r < rows)
          out[(size_t)sidx[r]*OUTF + col] = acc2[mf][j] + bias2;
      }
    }
  }
}

extern "C" void kernel_launch(void* const* d_in, const int* in_sizes, int n_in,
                              void* d_out, int out_size, void* d_ws, size_t ws_size,
                              hipStream_t stream) {
  const float* x  = (const float*)d_in[0];
  const int*   cam= (const int*)d_in[1];
  const float* W1 = (const float*)d_in[2];
  const float* b1 = (const float*)d_in[3];
  const float* W2 = (const float*)d_in[4];
  const float* b2 = (const float*)d_in[5];
  float* out = (float*)d_out;

  char* ws = (char*)d_ws;
  int* counts     = (int*)(ws);          // 16 ints
  int* scatterOfs = (int*)(ws + 64);     // 16 ints
  int* offsets    = (int*)(ws + 128);    // 17 ints
  int* idx        = (int*)(ws + 256);    // BB ints (1 MB)
  unsigned short* W1p = (unsigned short*)(ws + 256 + (size_t)BB*4);       // 983040 B
  unsigned short* W2p = W1p + (size_t)NCAM*8*8*64*8;                      // 61440 B

  (void)hipMemsetAsync(counts, 0, 64, stream);
  hipLaunchKernelGGL(k_hist,    dim3(1024), dim3(256), 0, stream, cam, counts, BB);
  hipLaunchKernelGGL(k_scan,    dim3(1),    dim3(64),  0, stream, counts, offsets, scatterOfs);
  hipLaunchKernelGGL(k_scatter, dim3(BB/4096), dim3(256), 0, stream, cam, scatterOfs, idx, BB);
  hipLaunchKernelGGL(k_prepW1,  dim3(240),  dim3(256), 0, stream, W1, W1p);
  hipLaunchKernelGGL(k_prepW2,  dim3(15),   dim3(256), 0, stream, W2, W2p);
  hipLaunchKernelGGL(k_mlp,     dim3(MAXTILES), dim3(256), 0, stream,
                     x, idx, counts, offsets, W1p, W2p, b1, b2, out);
}